// Round 4
// baseline (887.929 us; speedup 1.0000x reference)
//
#include <hip/hip_runtime.h>
#include <hip/hip_bf16.h>
#include <math.h>

#define NB 131072

typedef __attribute__((ext_vector_type(4))) float f32x4;
typedef __attribute__((ext_vector_type(8))) short bf16x8;

// zero-instruction wave-local ordering fence: LDS here is wave-private, DS ops
// are in-order per wave, so we only need to stop compiler reordering.
#define SYNC() do { asm volatile("" ::: "memory"); __builtin_amdgcn_sched_barrier(0); } while (0)

// ---- workspace layout (float offsets) ----
#define WS_A_EEG 0          // [64][32]
#define WS_A_EOG 2048       // [64][32]
#define WS_B0    4096       // [64]
#define WS_WATT  4160       // [2][64][64] f32 (fallback)
#define WS_BATT  12352      // [2][64]
#define WS_WVT   12480      // [62][62]  (fallback)
#define WS_M     16324      // [62][62]
#define WS_OBB   20168      // [62]
#define WS_CWT   20232      // [62][32][5]
#define WS_CWOG  30152      // [33][32]
#define WS_W2T   31208      // [2][256][64] f32 (fallback)
#define WB_WA_F  64000      // bf16 [2][64][64]   (4096 floats)
#define WB_W1_F  68096      // bf16 [2][256][64]  (16384 floats)
#define WB_W2_F  84480      // bf16 [2][64][256]  (16384 floats)
#define WS_EEGT  100864                   // [310][B]
#define WS_POOL  (WS_EEGT + 310 * NB)     // [62][B]
#define WS_EOGT  (WS_POOL + 62 * NB)      // [33][B]
#define WS_TOTALF (WS_EOGT + 33 * NB)

// per-wave LDS: 64 rows x 208B (13 granules of 16B; odd stride -> <=2-way banks)
//   H  bf16 granules 0..7 (128B), G bf16 granules 8..11 (64B),
//   C  f32 relayout reuses granules 0..7 in two 32-col halves.
#define ROWB 208
#define WAVE_LDS (64 * ROWB)

__device__ __forceinline__ short f2bf(float x) {
    union { __hip_bfloat16 h; short s; } u;
    u.h = __float2bfloat16(x);
    return u.s;
}

__global__ __launch_bounds__(256) void mcaf_pre(
    const float* __restrict__ eeg_inw, const float* __restrict__ eeg_inb,
    const float* __restrict__ eeg_ow,  const float* __restrict__ eeg_ob,
    const float* __restrict__ eeg_cw,
    const float* __restrict__ eeg_fw,  const float* __restrict__ eeg_fb,
    const float* __restrict__ eog_cw,  const float* __restrict__ eog_fw,
    const float* __restrict__ eog_fb,
    const float* __restrict__ fus_w,   const float* __restrict__ fus_b,
    const float* __restrict__ tl_inw,  const float* __restrict__ tl_inb,
    const float* __restrict__ tl_ow,   const float* __restrict__ tl_ob,
    const float* __restrict__ tl_w1,   const float* __restrict__ tl_w2,
    float* __restrict__ ws)
{
    const int tid  = blockIdx.x * blockDim.x + threadIdx.x;
    const int nthr = gridDim.x * blockDim.x;
    short* wa_b = (short*)(ws + WB_WA_F);
    short* w1_b = (short*)(ws + WB_W1_F);
    short* w2_b = (short*)(ws + WB_W2_F);

    for (int idx = tid; idx < 2048; idx += nthr) {
        int f = idx >> 5, o = idx & 31;
        float a = 0.f, a2 = 0.f;
        for (int k = 0; k < 64; ++k) {
            a  = fmaf(fus_w[f * 128 + k],      eeg_fw[k * 32 + o], a);
            a2 = fmaf(fus_w[f * 128 + 64 + k], eog_fw[k * 32 + o], a2);
        }
        ws[WS_A_EEG + idx] = a;
        ws[WS_A_EOG + idx] = a2;
    }
    for (int f = tid; f < 64; f += nthr) {
        float a = fus_b[f] + (float)(f & 1);
        for (int k = 0; k < 64; ++k) {
            a = fmaf(fus_w[f * 128 + k],      eeg_fb[k], a);
            a = fmaf(fus_w[f * 128 + 64 + k], eog_fb[k], a);
        }
        ws[WS_B0 + f] = a;
    }
    for (int idx = tid; idx < 8192; idx += nthr) {
        int i = idx >> 12, c = (idx >> 6) & 63, d = idx & 63;
        float a = 0.f;
        for (int e = 0; e < 64; ++e)
            a = fmaf(tl_ow[i * 4096 + c * 64 + e],
                     tl_inw[i * 12288 + (128 + e) * 64 + d], a);
        ws[WS_WATT + idx] = a;
        wa_b[idx] = f2bf(a);
    }
    for (int idx = tid; idx < 128; idx += nthr) {
        int i = idx >> 6, c = idx & 63;
        float a = tl_ob[i * 64 + c];
        for (int e = 0; e < 64; ++e)
            a = fmaf(tl_ow[i * 4096 + c * 64 + e], tl_inb[i * 192 + 128 + e], a);
        ws[WS_BATT + idx] = a;
    }
    for (int idx = tid; idx < 32768; idx += nthr) w1_b[idx] = f2bf(tl_w1[idx]);
    for (int idx = tid; idx < 32768; idx += nthr) w2_b[idx] = f2bf(tl_w2[idx]);

    for (int idx = tid; idx < 3844; idx += nthr) {
        int e = idx / 62, d = idx - e * 62;
        ws[WS_WVT + idx] = eeg_inw[(124 + d) * 62 + e];
    }
    for (int idx = tid; idx < 3844; idx += nthr) {
        int c = idx / 62, e = idx - c * 62;
        float a = 0.f;
        for (int d = 0; d < 62; ++d)
            a = fmaf(eeg_ow[c * 62 + d], eeg_inw[(124 + d) * 62 + e], a);
        ws[WS_M + idx] = a;
    }
    for (int c = tid; c < 62; c += nthr) {
        float a = eeg_ob[c];
        for (int d = 0; d < 62; ++d)
            a = fmaf(eeg_ow[c * 62 + d], eeg_inb[124 + d], a);
        ws[WS_OBB + c] = a;
    }
    for (int idx = tid; idx < 9920; idx += nthr) {
        int c = idx / 160, r = idx - c * 160;
        int o = r / 5, l = r - o * 5;
        ws[WS_CWT + idx] = eeg_cw[o * 310 + c * 5 + l];
    }
    for (int idx = tid; idx < 1056; idx += nthr) {
        int l = idx >> 5, o = idx & 31;
        ws[WS_CWOG + idx] = eog_cw[o * 33 + l];
    }
    for (int idx = tid; idx < 32768; idx += nthr) {
        int i = idx >> 14, r = idx & 16383;
        int j = r >> 6, c = r & 63;
        ws[WS_W2T + idx] = tl_w2[i * 16384 + c * 256 + j];
    }
}

// ---- eeg transpose + fused pooling (wave-private LDS, no barriers) ----
__global__ __launch_bounds__(256) void eeg_tr(const float* __restrict__ eeg,
                                              float* __restrict__ ws)
{
    __shared__ float smem[4 * 64 * 41];
    const int lane  = threadIdx.x & 63;
    const int wid   = threadIdx.x >> 6;
    const int chunk = blockIdx.x & 7;
    const int bw    = (blockIdx.x >> 3) * 256 + wid * 64;
    float* sw = smem + wid * (64 * 41);

    const int ch0 = chunk * 40;
    for (int j = 0; j < 40; ++j) {
        int idx = j * 64 + lane;
        int r = idx / 40, cc = idx - r * 40;
        int gcol = ch0 + cc;
        float v = 0.f;
        if (gcol < 310) v = eeg[(bw + r) * 310 + gcol];
        sw[r * 41 + cc] = v;
    }
    SYNC();
    #pragma unroll
    for (int cc = 0; cc < 40; ++cc) {
        int gcol = ch0 + cc;
        if (gcol < 310)
            ws[WS_EEGT + gcol * NB + bw + lane] = sw[lane * 41 + cc];
    }
    #pragma unroll
    for (int el = 0; el < 8; ++el) {
        int e = chunk * 8 + el;
        if (e < 62) {
            const float* xr = sw + lane * 41 + el * 5;
            float p = (xr[0] + xr[1] + xr[2] + xr[3] + xr[4]) * 0.2f;
            ws[WS_POOL + e * NB + bw + lane] = p;
        }
    }
}

__global__ __launch_bounds__(256) void eog_tr(const float* __restrict__ eog,
                                              float* __restrict__ ws)
{
    __shared__ float smem[4 * 64 * 34];
    const int lane = threadIdx.x & 63;
    const int wid  = threadIdx.x >> 6;
    const int bw   = blockIdx.x * 256 + wid * 64;
    float* sw = smem + wid * (64 * 34);

    for (int j = 0; j < 33; ++j) {
        int idx = j * 64 + lane;
        int r = idx / 33, cc = idx - r * 33;
        sw[r * 34 + cc] = eog[(bw + r) * 33 + cc];
    }
    SYNC();
    #pragma unroll
    for (int cc = 0; cc < 33; ++cc)
        ws[WS_EOGT + cc * NB + bw + lane] = sw[lane * 34 + cc];
}

// ================= MFMA main kernel (barrier-free, wave-private LDS) =========
__global__ __launch_bounds__(256) void mcaf_main_t(
    const float* __restrict__ eeg_cb,
    const float* __restrict__ eog_inw, const float* __restrict__ eog_inb,
    const float* __restrict__ eog_ow,  const float* __restrict__ eog_ob,
    const float* __restrict__ eog_cb,
    const float* __restrict__ tl_ln1_s, const float* __restrict__ tl_ln1_b,
    const float* __restrict__ tl_ln2_s, const float* __restrict__ tl_ln2_b,
    const float* __restrict__ tl_b1,   const float* __restrict__ tl_b2,
    const float* __restrict__ fn_s,    const float* __restrict__ fn_b,
    const float* __restrict__ cls_w,   const float* __restrict__ cls_b,
    const float* __restrict__ ws,      float* __restrict__ out)
{
    __shared__ char smem[4 * WAVE_LDS];   // 53248 B -> 3 blocks/CU
    const int tid  = threadIdx.x;
    const int lane = tid & 63;
    const int wid  = tid >> 6;
    const int b    = blockIdx.x * 256 + tid;
    char* Wv = smem + wid * WAVE_LDS;
    const int g4  = lane >> 4;
    const int r15 = lane & 15;

    // ---- EEG front-end (per-lane, transposed inputs) ----
    float pooled[62];
    #pragma unroll
    for (int e = 0; e < 62; ++e) pooled[e] = ws[WS_POOL + e * NB + b];

    float h[32];
    #pragma unroll
    for (int o = 0; o < 32; ++o) h[o] = eeg_cb[o];

    for (int c = 0; c < 62; ++c) {
        const float* Mr = ws + WS_M + c * 62;
        float oc0 = ws[WS_OBB + c], oc1 = 0.f;
        #pragma unroll
        for (int e = 0; e < 62; e += 2) {
            oc0 = fmaf(Mr[e],     pooled[e],     oc0);
            oc1 = fmaf(Mr[e + 1], pooled[e + 1], oc1);
        }
        float oc = oc0 + oc1;
        const float* xb = ws + WS_EEGT + c * 5 * NB + b;
        float x0 = xb[0], x1 = xb[NB], x2 = xb[2 * NB], x3 = xb[3 * NB], x4 = xb[4 * NB];
        const float* cwr = ws + WS_CWT + c * 160;
        #pragma unroll
        for (int o = 0; o < 32; ++o) {
            float tt = x0 * cwr[o * 5 + 0];
            tt = fmaf(x1, cwr[o * 5 + 1], tt);
            tt = fmaf(x2, cwr[o * 5 + 2], tt);
            tt = fmaf(x3, cwr[o * 5 + 3], tt);
            tt = fmaf(x4, cwr[o * 5 + 4], tt);
            h[o] = fmaf(oc, tt, h[o]);
        }
    }
    #pragma unroll
    for (int o = 0; o < 32; ++o) h[o] = h[o] > 0.f ? h[o] : expm1f(h[o]);

    float feat[64];
    #pragma unroll
    for (int f = 0; f < 64; ++f) {
        float acc = ws[WS_B0 + f];
        #pragma unroll
        for (int o = 0; o < 32; ++o)
            acc = fmaf(ws[WS_A_EEG + f * 32 + o], h[o], acc);
        feat[f] = acc;
    }

    // ---- EOG branch ----
    {
        float Tg[32];
        #pragma unroll
        for (int o = 0; o < 32; ++o) Tg[o] = 0.f;
        float pool = 0.f;
        for (int l2 = 0; l2 < 33; ++l2) {
            float x = ws[WS_EOGT + l2 * NB + b];
            pool += x;
            const float* cr = ws + WS_CWOG + l2 * 32;
            #pragma unroll
            for (int o = 0; o < 32; ++o) Tg[o] = fmaf(x, cr[o], Tg[o]);
        }
        pool *= (1.f / 33.f);
        float vb2 = fmaf(pool, eog_inw[2], eog_inb[2]);
        float ob2 = fmaf(vb2, eog_ow[0], eog_ob[0]);
        #pragma unroll
        for (int o = 0; o < 32; ++o) {
            float hh = fmaf(ob2, Tg[o], eog_cb[o]);
            Tg[o] = hh > 0.f ? hh : expm1f(hh);
        }
        #pragma unroll
        for (int f = 0; f < 64; ++f) {
            float acc = feat[f];
            #pragma unroll
            for (int o = 0; o < 32; ++o)
                acc = fmaf(ws[WS_A_EOG + f * 32 + o], Tg[o], acc);
            feat[f] = acc;
        }
    }

    // ---- transformer: wave-cooperative MFMA, no block barriers ----
    const short* WAb = (const short*)(ws + WB_WA_F);
    const short* W1b = (const short*)(ws + WB_W1_F);
    const short* W2b = (const short*)(ws + WB_W2_F);

    for (int i2 = 0; i2 < 2; ++i2) {
        const float* ba  = ws + WS_BATT + i2 * 64;
        const float* s1  = tl_ln1_s + i2 * 64;
        const float* gb1 = tl_ln1_b + i2 * 64;
        const float* s2  = tl_ln2_s + i2 * 64;
        const float* gb2 = tl_ln2_b + i2 * 64;
        const float* bf1 = tl_b1 + i2 * 256;
        const float* bf2 = tl_b2 + i2 * 64;

        float hb[64];
        // LN1
        {
            float m = 0.f;
            #pragma unroll
            for (int d = 0; d < 64; ++d) m += feat[d];
            m *= 0.015625f;
            float vv = 0.f;
            #pragma unroll
            for (int d = 0; d < 64; ++d) { float u = feat[d] - m; vv = fmaf(u, u, vv); }
            vv *= 0.015625f;
            float inv = rsqrtf(vv + 1e-5f);
            #pragma unroll
            for (int d = 0; d < 64; ++d)
                hb[d] = fmaf((feat[d] - m) * inv, s1[d], gb1[d]);
        }
        // stage H rows (granules 0..7)
        #pragma unroll
        for (int jj = 0; jj < 8; ++jj) {
            bf16x8 v;
            #pragma unroll
            for (int e = 0; e < 8; ++e) v[e] = f2bf(hb[jj * 8 + e]);
            *(bf16x8*)(Wv + lane * ROWB + jj * 16) = v;
        }
        SYNC();
        bf16x8 Aat[4][2];
        #pragma unroll
        for (int rt = 0; rt < 4; ++rt)
            #pragma unroll
            for (int kt = 0; kt < 2; ++kt)
                Aat[rt][kt] = *(const bf16x8*)(Wv + (rt * 16 + r15) * ROWB + (kt * 4 + g4) * 16);
        SYNC();
        // attn GEMM: 64x64x64
        f32x4 acc[4][4];
        #pragma unroll
        for (int rt = 0; rt < 4; ++rt)
            #pragma unroll
            for (int ct = 0; ct < 4; ++ct) acc[rt][ct] = (f32x4){0.f, 0.f, 0.f, 0.f};
        #pragma unroll
        for (int kt = 0; kt < 2; ++kt) {
            bf16x8 bb[4];
            #pragma unroll
            for (int ct = 0; ct < 4; ++ct)
                bb[ct] = *(const bf16x8*)(WAb + i2 * 4096 + (ct * 16 + r15) * 64 + kt * 32 + g4 * 8);
            #pragma unroll
            for (int rt = 0; rt < 4; ++rt)
                #pragma unroll
                for (int ct = 0; ct < 4; ++ct)
                    acc[rt][ct] = __builtin_amdgcn_mfma_f32_16x16x32_bf16(Aat[rt][kt], bb[ct], acc[rt][ct], 0, 0, 0);
        }
        // C relayout in two 32-col halves over granules 0..7, + residual + bias
        #pragma unroll
        for (int hf = 0; hf < 2; ++hf) {
            SYNC();
            #pragma unroll
            for (int ct2 = 0; ct2 < 2; ++ct2) {
                int ct = hf * 2 + ct2;
                #pragma unroll
                for (int rt = 0; rt < 4; ++rt)
                    #pragma unroll
                    for (int rg = 0; rg < 4; ++rg) {
                        int row = rt * 16 + g4 * 4 + rg;
                        int lc  = ct2 * 16 + r15;
                        *(float*)(Wv + row * ROWB + lc * 4) = acc[rt][ct][rg];
                    }
            }
            SYNC();
            #pragma unroll
            for (int j8 = 0; j8 < 8; ++j8) {
                f32x4 v = *(const f32x4*)(Wv + lane * ROWB + j8 * 16);
                #pragma unroll
                for (int e = 0; e < 4; ++e) {
                    int d = hf * 32 + j8 * 4 + e;
                    feat[d] += v[e] + ba[d];
                }
            }
        }
        // LN2
        {
            float m = 0.f;
            #pragma unroll
            for (int d = 0; d < 64; ++d) m += feat[d];
            m *= 0.015625f;
            float vv = 0.f;
            #pragma unroll
            for (int d = 0; d < 64; ++d) { float u = feat[d] - m; vv = fmaf(u, u, vv); }
            vv *= 0.015625f;
            float inv = rsqrtf(vv + 1e-5f);
            #pragma unroll
            for (int d = 0; d < 64; ++d)
                hb[d] = fmaf((feat[d] - m) * inv, s2[d], gb2[d]);
        }
        SYNC();
        #pragma unroll
        for (int jj = 0; jj < 8; ++jj) {
            bf16x8 v;
            #pragma unroll
            for (int e = 0; e < 8; ++e) v[e] = f2bf(hb[jj * 8 + e]);
            *(bf16x8*)(Wv + lane * ROWB + jj * 16) = v;
        }
        SYNC();
        // FFN: 8 chunks of 32 hidden; F accumulates FFN2
        f32x4 F[4][4];
        #pragma unroll
        for (int rt = 0; rt < 4; ++rt)
            #pragma unroll
            for (int ct = 0; ct < 4; ++ct) F[rt][ct] = (f32x4){0.f, 0.f, 0.f, 0.f};

        for (int ch = 0; ch < 8; ++ch) {
            f32x4 G[4][2];
            #pragma unroll
            for (int rt = 0; rt < 4; ++rt) {
                G[rt][0] = (f32x4){0.f, 0.f, 0.f, 0.f};
                G[rt][1] = (f32x4){0.f, 0.f, 0.f, 0.f};
            }
            #pragma unroll
            for (int kt = 0; kt < 2; ++kt) {
                bf16x8 a1[4];
                #pragma unroll
                for (int rt = 0; rt < 4; ++rt)
                    a1[rt] = *(const bf16x8*)(Wv + (rt * 16 + r15) * ROWB + (kt * 4 + g4) * 16);
                bf16x8 b1[2];
                #pragma unroll
                for (int cc = 0; cc < 2; ++cc)
                    b1[cc] = *(const bf16x8*)(W1b + i2 * 16384 + (ch * 32 + cc * 16 + r15) * 64 + kt * 32 + g4 * 8);
                #pragma unroll
                for (int rt = 0; rt < 4; ++rt)
                    #pragma unroll
                    for (int cc = 0; cc < 2; ++cc)
                        G[rt][cc] = __builtin_amdgcn_mfma_f32_16x16x32_bf16(a1[rt], b1[cc], G[rt][cc], 0, 0, 0);
            }
            SYNC();
            // bias + gelu -> G' bf16 (granules 8..11)
            #pragma unroll
            for (int rt = 0; rt < 4; ++rt)
                #pragma unroll
                for (int cc = 0; cc < 2; ++cc) {
                    float bj = bf1[ch * 32 + cc * 16 + r15];
                    #pragma unroll
                    for (int rg = 0; rg < 4; ++rg) {
                        float v = G[rt][cc][rg] + bj;
                        v = 0.5f * v * (1.f + erff(v * 0.70710678118654752f));
                        int row = rt * 16 + g4 * 4 + rg;
                        int col = cc * 16 + r15;
                        *(short*)(Wv + row * ROWB + 128 + ((col >> 3) << 4) + ((col & 7) << 1)) = f2bf(v);
                    }
                }
            SYNC();
            bf16x8 a2[4], b2[4];
            #pragma unroll
            for (int rt = 0; rt < 4; ++rt)
                a2[rt] = *(const bf16x8*)(Wv + (rt * 16 + r15) * ROWB + 128 + g4 * 16);
            #pragma unroll
            for (int ct = 0; ct < 4; ++ct)
                b2[ct] = *(const bf16x8*)(W2b + i2 * 16384 + (ct * 16 + r15) * 256 + ch * 32 + g4 * 8);
            #pragma unroll
            for (int rt = 0; rt < 4; ++rt)
                #pragma unroll
                for (int ct = 0; ct < 4; ++ct)
                    F[rt][ct] = __builtin_amdgcn_mfma_f32_16x16x32_bf16(a2[rt], b2[ct], F[rt][ct], 0, 0, 0);
            SYNC();   // order a2 reads before next chunk's G' writes
        }
        // F relayout halves + residual + b2 bias
        #pragma unroll
        for (int hf = 0; hf < 2; ++hf) {
            SYNC();
            #pragma unroll
            for (int ct2 = 0; ct2 < 2; ++ct2) {
                int ct = hf * 2 + ct2;
                #pragma unroll
                for (int rt = 0; rt < 4; ++rt)
                    #pragma unroll
                    for (int rg = 0; rg < 4; ++rg) {
                        int row = rt * 16 + g4 * 4 + rg;
                        int lc  = ct2 * 16 + r15;
                        *(float*)(Wv + row * ROWB + lc * 4) = F[rt][ct][rg];
                    }
            }
            SYNC();
            #pragma unroll
            for (int j8 = 0; j8 < 8; ++j8) {
                f32x4 v = *(const f32x4*)(Wv + lane * ROWB + j8 * 16);
                #pragma unroll
                for (int e = 0; e < 4; ++e) {
                    int d = hf * 32 + j8 * 4 + e;
                    feat[d] += v[e] + bf2[d];
                }
            }
        }
        SYNC();
    }

    // ---- final LN + classifier ----
    {
        float m = 0.f;
        #pragma unroll
        for (int d = 0; d < 64; ++d) m += feat[d];
        m *= 0.015625f;
        float vv = 0.f;
        #pragma unroll
        for (int d = 0; d < 64; ++d) { float u = feat[d] - m; vv = fmaf(u, u, vv); }
        vv *= 0.015625f;
        float inv = rsqrtf(vv + 1e-5f);
        float o0 = cls_b[0], o1 = cls_b[1], o2 = cls_b[2];
        #pragma unroll
        for (int d = 0; d < 64; ++d) {
            float n = fmaf((feat[d] - m) * inv, fn_s[d], fn_b[d]);
            o0 = fmaf(n, cls_w[d], o0);
            o1 = fmaf(n, cls_w[64 + d], o1);
            o2 = fmaf(n, cls_w[128 + d], o2);
        }
        float* op = out + b * 3;
        op[0] = o0; op[1] = o1; op[2] = o2;
    }
}

// ================= fallback main kernel (fp32, LDS staging) =================
__global__ __launch_bounds__(256, 2) void mcaf_main_fb(
    const float* __restrict__ eeg,     const float* __restrict__ eog,
    const float* __restrict__ eeg_inb,
    const float* __restrict__ eeg_ow,  const float* __restrict__ eeg_ob,
    const float* __restrict__ eog_inw, const float* __restrict__ eog_inb,
    const float* __restrict__ eog_ow,  const float* __restrict__ eog_ob,
    const float* __restrict__ eeg_cb,  const float* __restrict__ eog_cb,
    const float* __restrict__ tl_ln1_s, const float* __restrict__ tl_ln1_b,
    const float* __restrict__ tl_ln2_s, const float* __restrict__ tl_ln2_b,
    const float* __restrict__ tl_w1,   const float* __restrict__ tl_b1,
    const float* __restrict__ tl_b2,
    const float* __restrict__ fn_s,    const float* __restrict__ fn_b,
    const float* __restrict__ cls_w,   const float* __restrict__ cls_b,
    const float* __restrict__ ws,      float* __restrict__ out)
{
    __shared__ float smem[4 * 64 * 41];
    const int t    = threadIdx.x;
    const int lane = t & 63;
    const int wid  = t >> 6;
    const int bw   = blockIdx.x * 256 + wid * 64;
    const int b    = bw + lane;
    float* sw = smem + wid * (64 * 41);

    float vbar[62];
    #pragma unroll
    for (int d = 0; d < 62; ++d) vbar[d] = eeg_inb[124 + d];

    for (int chunk = 0; chunk < 8; ++chunk) {
        const int ch0 = chunk * 8;
        for (int j = 0; j < 40; ++j) {
            int idx = j * 64 + lane;
            int r = idx / 40, cc = idx - r * 40;
            int gcol = ch0 * 5 + cc;
            float v = 0.f;
            if (gcol < 310) v = eeg[(bw + r) * 310 + gcol];
            sw[r * 41 + cc] = v;
        }
        __syncthreads();
        const int nch = (62 - ch0 < 8) ? (62 - ch0) : 8;
        for (int el = 0; el < nch; ++el) {
            const int e = ch0 + el;
            const float* xr = sw + lane * 41 + el * 5;
            float p = (xr[0] + xr[1] + xr[2] + xr[3] + xr[4]) * 0.2f;
            const float* wr = ws + WS_WVT + e * 62;
            #pragma unroll
            for (int d = 0; d < 62; ++d) vbar[d] = fmaf(p, wr[d], vbar[d]);
        }
        __syncthreads();
    }

    float h[32];
    #pragma unroll
    for (int o = 0; o < 32; ++o) h[o] = eeg_cb[o];

    for (int chunk = 0; chunk < 8; ++chunk) {
        const int ch0 = chunk * 8;
        for (int j = 0; j < 40; ++j) {
            int idx = j * 64 + lane;
            int r = idx / 40, cc = idx - r * 40;
            int gcol = ch0 * 5 + cc;
            float v = 0.f;
            if (gcol < 310) v = eeg[(bw + r) * 310 + gcol];
            sw[r * 41 + cc] = v;
        }
        __syncthreads();
        const int nch = (62 - ch0 < 8) ? (62 - ch0) : 8;
        for (int el = 0; el < nch; ++el) {
            const int c = ch0 + el;
            const float* owr = eeg_ow + c * 62;
            float oc = eeg_ob[c];
            #pragma unroll
            for (int d = 0; d < 62; ++d) oc = fmaf(owr[d], vbar[d], oc);
            const float* xr = sw + lane * 41 + el * 5;
            float x0 = xr[0], x1 = xr[1], x2 = xr[2], x3 = xr[3], x4 = xr[4];
            const float* cwr = ws + WS_CWT + c * 160;
            #pragma unroll
            for (int o = 0; o < 32; ++o) {
                float tt = x0 * cwr[o * 5 + 0];
                tt = fmaf(x1, cwr[o * 5 + 1], tt);
                tt = fmaf(x2, cwr[o * 5 + 2], tt);
                tt = fmaf(x3, cwr[o * 5 + 3], tt);
                tt = fmaf(x4, cwr[o * 5 + 4], tt);
                h[o] = fmaf(oc, tt, h[o]);
            }
        }
        __syncthreads();
    }

    #pragma unroll
    for (int o = 0; o < 32; ++o) h[o] = h[o] > 0.f ? h[o] : expm1f(h[o]);

    float feat[64];
    #pragma unroll
    for (int f = 0; f < 64; ++f) {
        float acc = ws[WS_B0 + f];
        #pragma unroll
        for (int o = 0; o < 32; ++o)
            acc = fmaf(ws[WS_A_EEG + f * 32 + o], h[o], acc);
        feat[f] = acc;
    }

    for (int j = 0; j < 33; ++j) {
        int idx = j * 64 + lane;
        int r = idx / 33, cc = idx - r * 33;
        sw[r * 34 + cc] = eog[(bw + r) * 33 + cc];
    }
    __syncthreads();
    {
        float Tg[32];
        #pragma unroll
        for (int o = 0; o < 32; ++o) Tg[o] = 0.f;
        float pool = 0.f;
        for (int l2 = 0; l2 < 33; ++l2) {
            float x = sw[lane * 34 + l2];
            pool += x;
            const float* cr = ws + WS_CWOG + l2 * 32;
            #pragma unroll
            for (int o = 0; o < 32; ++o) Tg[o] = fmaf(x, cr[o], Tg[o]);
        }
        pool *= (1.f / 33.f);
        float vb2 = fmaf(pool, eog_inw[2], eog_inb[2]);
        float ob2 = fmaf(vb2, eog_ow[0], eog_ob[0]);
        #pragma unroll
        for (int o = 0; o < 32; ++o) {
            float hh = fmaf(ob2, Tg[o], eog_cb[o]);
            Tg[o] = hh > 0.f ? hh : expm1f(hh);
        }
        #pragma unroll
        for (int f = 0; f < 64; ++f) {
            float acc = feat[f];
            #pragma unroll
            for (int o = 0; o < 32; ++o)
                acc = fmaf(ws[WS_A_EOG + f * 32 + o], Tg[o], acc);
            feat[f] = acc;
        }
    }

    for (int i2 = 0; i2 < 2; ++i2) {
        const float* Wa  = ws + WS_WATT + i2 * 4096;
        const float* ba  = ws + WS_BATT + i2 * 64;
        const float* s1  = tl_ln1_s + i2 * 64;
        const float* g1  = tl_ln1_b + i2 * 64;
        const float* s2  = tl_ln2_s + i2 * 64;
        const float* g2  = tl_ln2_b + i2 * 64;
        const float* w1p = tl_w1 + i2 * 16384;
        const float* bf1 = tl_b1 + i2 * 256;
        const float* w2t = ws + WS_W2T + i2 * 16384;
        const float* bf2 = tl_b2 + i2 * 64;

        float hb[64];
        {
            float m = 0.f;
            #pragma unroll
            for (int d = 0; d < 64; ++d) m += feat[d];
            m *= 0.015625f;
            float vv = 0.f;
            #pragma unroll
            for (int d = 0; d < 64; ++d) { float u = feat[d] - m; vv = fmaf(u, u, vv); }
            vv *= 0.015625f;
            float inv = rsqrtf(vv + 1e-5f);
            #pragma unroll
            for (int d = 0; d < 64; ++d)
                hb[d] = fmaf((feat[d] - m) * inv, s1[d], g1[d]);
        }
        #pragma unroll
        for (int c = 0; c < 64; ++c) {
            float a = ba[c];
            #pragma unroll
            for (int d = 0; d < 64; ++d) a = fmaf(Wa[c * 64 + d], hb[d], a);
            feat[c] += a;
        }
        {
            float m = 0.f;
            #pragma unroll
            for (int d = 0; d < 64; ++d) m += feat[d];
            m *= 0.015625f;
            float vv = 0.f;
            #pragma unroll
            for (int d = 0; d < 64; ++d) { float u = feat[d] - m; vv = fmaf(u, u, vv); }
            vv *= 0.015625f;
            float inv = rsqrtf(vv + 1e-5f);
            #pragma unroll
            for (int d = 0; d < 64; ++d)
                hb[d] = fmaf((feat[d] - m) * inv, s2[d], g2[d]);
        }
        #pragma unroll
        for (int c = 0; c < 64; ++c) feat[c] += bf2[c];
        for (int j = 0; j < 256; ++j) {
            const float* wr = w1p + j * 64;
            float g = bf1[j];
            #pragma unroll
            for (int d = 0; d < 64; ++d) g = fmaf(wr[d], hb[d], g);
            g = 0.5f * g * (1.f + erff(g * 0.70710678118654752f));
            const float* w2r = w2t + j * 64;
            #pragma unroll
            for (int c = 0; c < 64; ++c) feat[c] = fmaf(g, w2r[c], feat[c]);
        }
    }

    {
        float m = 0.f;
        #pragma unroll
        for (int d = 0; d < 64; ++d) m += feat[d];
        m *= 0.015625f;
        float vv = 0.f;
        #pragma unroll
        for (int d = 0; d < 64; ++d) { float u = feat[d] - m; vv = fmaf(u, u, vv); }
        vv *= 0.015625f;
        float inv = rsqrtf(vv + 1e-5f);
        float o0 = cls_b[0], o1 = cls_b[1], o2 = cls_b[2];
        #pragma unroll
        for (int d = 0; d < 64; ++d) {
            float n = fmaf((feat[d] - m) * inv, fn_s[d], fn_b[d]);
            o0 = fmaf(n, cls_w[d], o0);
            o1 = fmaf(n, cls_w[64 + d], o1);
            o2 = fmaf(n, cls_w[128 + d], o2);
        }
        float* op = out + b * 3;
        op[0] = o0; op[1] = o1; op[2] = o2;
    }
}

extern "C" void kernel_launch(void* const* d_in, const int* in_sizes, int n_in,
                              void* d_out, int out_size, void* d_ws, size_t ws_size,
                              hipStream_t stream) {
    const float* eeg      = (const float*)d_in[0];
    const float* eog      = (const float*)d_in[1];
    const float* eeg_inw  = (const float*)d_in[2];
    const float* eeg_inb  = (const float*)d_in[3];
    const float* eeg_ow   = (const float*)d_in[4];
    const float* eeg_ob   = (const float*)d_in[5];
    const float* eog_inw  = (const float*)d_in[6];
    const float* eog_inb  = (const float*)d_in[7];
    const float* eog_ow   = (const float*)d_in[8];
    const float* eog_ob   = (const float*)d_in[9];
    const float* eeg_cw   = (const float*)d_in[10];
    const float* eeg_cb   = (const float*)d_in[11];
    const float* eeg_fw   = (const float*)d_in[12];
    const float* eeg_fb   = (const float*)d_in[13];
    const float* eog_cw   = (const float*)d_in[14];
    const float* eog_cb   = (const float*)d_in[15];
    const float* eog_fw   = (const float*)d_in[16];
    const float* eog_fb   = (const float*)d_in[17];
    const float* fus_w    = (const float*)d_in[18];
    const float* fus_b    = (const float*)d_in[19];
    const float* tl_ln1_s = (const float*)d_in[20];
    const float* tl_ln1_b = (const float*)d_in[21];
    const float* tl_inw   = (const float*)d_in[22];
    const float* tl_inb   = (const float*)d_in[23];
    const float* tl_ow    = (const float*)d_in[24];
    const float* tl_ob    = (const float*)d_in[25];
    const float* tl_ln2_s = (const float*)d_in[26];
    const float* tl_ln2_b = (const float*)d_in[27];
    const float* tl_w1    = (const float*)d_in[28];
    const float* tl_b1    = (const float*)d_in[29];
    const float* tl_w2    = (const float*)d_in[30];
    const float* tl_b2    = (const float*)d_in[31];
    const float* fn_s     = (const float*)d_in[32];
    const float* fn_b     = (const float*)d_in[33];
    const float* cls_w    = (const float*)d_in[34];
    const float* cls_b    = (const float*)d_in[35];
    float* ws  = (float*)d_ws;
    float* out = (float*)d_out;

    hipLaunchKernelGGL(mcaf_pre, dim3(8), dim3(256), 0, stream,
                       eeg_inw, eeg_inb, eeg_ow, eeg_ob, eeg_cw,
                       eeg_fw, eeg_fb, eog_cw, eog_fw, eog_fb,
                       fus_w, fus_b, tl_inw, tl_inb, tl_ow, tl_ob, tl_w1, tl_w2, ws);

    const size_t need = (size_t)WS_TOTALF * 4u;
    if (ws_size >= need) {
        hipLaunchKernelGGL(eeg_tr, dim3((NB / 256) * 8), dim3(256), 0, stream, eeg, ws);
        hipLaunchKernelGGL(eog_tr, dim3(NB / 256), dim3(256), 0, stream, eog, ws);
        hipLaunchKernelGGL(mcaf_main_t, dim3(NB / 256), dim3(256), 0, stream,
                           eeg_cb, eog_inw, eog_inb, eog_ow, eog_ob, eog_cb,
                           tl_ln1_s, tl_ln1_b, tl_ln2_s, tl_ln2_b,
                           tl_b1, tl_b2,
                           fn_s, fn_b, cls_w, cls_b, ws, out);
    } else {
        hipLaunchKernelGGL(mcaf_main_fb, dim3(NB / 256), dim3(256), 0, stream,
                           eeg, eog, eeg_inb, eeg_ow, eeg_ob,
                           eog_inw, eog_inb, eog_ow, eog_ob,
                           eeg_cb, eog_cb,
                           tl_ln1_s, tl_ln1_b, tl_ln2_s, tl_ln2_b,
                           tl_w1, tl_b1, tl_b2,
                           fn_s, fn_b, cls_w, cls_b, ws, out);
    }
}

// Round 5
// 587.841 us; speedup vs baseline: 1.5105x; 1.5105x over previous
//
#include <hip/hip_runtime.h>
#include <hip/hip_bf16.h>
#include <math.h>

#define NB 131072

typedef __attribute__((ext_vector_type(4))) float f32x4;
typedef __attribute__((ext_vector_type(8))) short bf16x8;

// Wave-local ordering fence for wave-private LDS: memory clobber stops IR
// reordering; sched_barrier(0x7F) pins DS ops only (ALU/VALU/SALU/MFMA/VMEM
// may cross) so the backend scheduler keeps register pressure down.
#define SYNC() do { asm volatile("" ::: "memory"); __builtin_amdgcn_sched_barrier(0x7F); } while (0)

// ---- workspace layout (float offsets) ----
#define WS_A_EEG 0          // [64][32]
#define WS_A_EOG 2048       // [64][32]
#define WS_B0    4096       // [64]
#define WS_WATT  4160       // [2][64][64] f32 (fallback)
#define WS_BATT  12352      // [2][64]
#define WS_WVT   12480      // [62][62]  (fallback)
#define WS_M     16324      // [62][62]
#define WS_OBB   20168      // [62]
#define WS_CWT   20232      // [62][32][5]
#define WS_CWOG  30152      // [33][32]
#define WS_W2T   31208      // [2][256][64] f32 (fallback)
#define WB_WA_F  64000      // bf16 [2][64][64]
#define WB_W1_F  68096      // bf16 [2][256][64]
#define WB_W2_F  84480      // bf16 [2][64][256]
#define WS_EEGT  100864                   // [310][B]
#define WS_POOL  (WS_EEGT + 310 * NB)     // [62][B]
#define WS_EOGT  (WS_POOL + 62 * NB)      // [33][B]
#define WS_TOTALF (WS_EOGT + 33 * NB)
// feat[64][B] reuses eegT cols 0..63: each batch column is only ever read by
// its own thread in mcaf_front, and all its reads precede the write.
#define WS_FEAT  WS_EEGT

// per-wave LDS: 64 rows x 208B (13 granules of 16B; odd stride -> <=2-way banks)
#define ROWB 208
#define WAVE_LDS (64 * ROWB)

__device__ __forceinline__ short f2bf(float x) {
    union { __hip_bfloat16 h; short s; } u;
    u.h = __float2bfloat16(x);
    return u.s;
}

__global__ __launch_bounds__(256) void mcaf_pre(
    const float* __restrict__ eeg_inw, const float* __restrict__ eeg_inb,
    const float* __restrict__ eeg_ow,  const float* __restrict__ eeg_ob,
    const float* __restrict__ eeg_cw,
    const float* __restrict__ eeg_fw,  const float* __restrict__ eeg_fb,
    const float* __restrict__ eog_cw,  const float* __restrict__ eog_fw,
    const float* __restrict__ eog_fb,
    const float* __restrict__ fus_w,   const float* __restrict__ fus_b,
    const float* __restrict__ tl_inw,  const float* __restrict__ tl_inb,
    const float* __restrict__ tl_ow,   const float* __restrict__ tl_ob,
    const float* __restrict__ tl_w1,   const float* __restrict__ tl_w2,
    float* __restrict__ ws)
{
    const int tid  = blockIdx.x * blockDim.x + threadIdx.x;
    const int nthr = gridDim.x * blockDim.x;
    short* wa_b = (short*)(ws + WB_WA_F);
    short* w1_b = (short*)(ws + WB_W1_F);
    short* w2_b = (short*)(ws + WB_W2_F);

    for (int idx = tid; idx < 2048; idx += nthr) {
        int f = idx >> 5, o = idx & 31;
        float a = 0.f, a2 = 0.f;
        for (int k = 0; k < 64; ++k) {
            a  = fmaf(fus_w[f * 128 + k],      eeg_fw[k * 32 + o], a);
            a2 = fmaf(fus_w[f * 128 + 64 + k], eog_fw[k * 32 + o], a2);
        }
        ws[WS_A_EEG + idx] = a;
        ws[WS_A_EOG + idx] = a2;
    }
    for (int f = tid; f < 64; f += nthr) {
        float a = fus_b[f] + (float)(f & 1);
        for (int k = 0; k < 64; ++k) {
            a = fmaf(fus_w[f * 128 + k],      eeg_fb[k], a);
            a = fmaf(fus_w[f * 128 + 64 + k], eog_fb[k], a);
        }
        ws[WS_B0 + f] = a;
    }
    for (int idx = tid; idx < 8192; idx += nthr) {
        int i = idx >> 12, c = (idx >> 6) & 63, d = idx & 63;
        float a = 0.f;
        for (int e = 0; e < 64; ++e)
            a = fmaf(tl_ow[i * 4096 + c * 64 + e],
                     tl_inw[i * 12288 + (128 + e) * 64 + d], a);
        ws[WS_WATT + idx] = a;
        wa_b[idx] = f2bf(a);
    }
    for (int idx = tid; idx < 128; idx += nthr) {
        int i = idx >> 6, c = idx & 63;
        float a = tl_ob[i * 64 + c];
        for (int e = 0; e < 64; ++e)
            a = fmaf(tl_ow[i * 4096 + c * 64 + e], tl_inb[i * 192 + 128 + e], a);
        ws[WS_BATT + idx] = a;
    }
    for (int idx = tid; idx < 32768; idx += nthr) w1_b[idx] = f2bf(tl_w1[idx]);
    for (int idx = tid; idx < 32768; idx += nthr) w2_b[idx] = f2bf(tl_w2[idx]);

    for (int idx = tid; idx < 3844; idx += nthr) {
        int e = idx / 62, d = idx - e * 62;
        ws[WS_WVT + idx] = eeg_inw[(124 + d) * 62 + e];
    }
    for (int idx = tid; idx < 3844; idx += nthr) {
        int c = idx / 62, e = idx - c * 62;
        float a = 0.f;
        for (int d = 0; d < 62; ++d)
            a = fmaf(eeg_ow[c * 62 + d], eeg_inw[(124 + d) * 62 + e], a);
        ws[WS_M + idx] = a;
    }
    for (int c = tid; c < 62; c += nthr) {
        float a = eeg_ob[c];
        for (int d = 0; d < 62; ++d)
            a = fmaf(eeg_ow[c * 62 + d], eeg_inb[124 + d], a);
        ws[WS_OBB + c] = a;
    }
    for (int idx = tid; idx < 9920; idx += nthr) {
        int c = idx / 160, r = idx - c * 160;
        int o = r / 5, l = r - o * 5;
        ws[WS_CWT + idx] = eeg_cw[o * 310 + c * 5 + l];
    }
    for (int idx = tid; idx < 1056; idx += nthr) {
        int l = idx >> 5, o = idx & 31;
        ws[WS_CWOG + idx] = eog_cw[o * 33 + l];
    }
    for (int idx = tid; idx < 32768; idx += nthr) {
        int i = idx >> 14, r = idx & 16383;
        int j = r >> 6, c = r & 63;
        ws[WS_W2T + idx] = tl_w2[i * 16384 + c * 256 + j];
    }
}

// ---- eeg transpose + fused pooling (wave-private LDS, no barriers) ----
__global__ __launch_bounds__(256) void eeg_tr(const float* __restrict__ eeg,
                                              float* __restrict__ ws)
{
    __shared__ float smem[4 * 64 * 41];
    const int lane  = threadIdx.x & 63;
    const int wid   = threadIdx.x >> 6;
    const int chunk = blockIdx.x & 7;
    const int bw    = (blockIdx.x >> 3) * 256 + wid * 64;
    float* sw = smem + wid * (64 * 41);

    const int ch0 = chunk * 40;
    for (int j = 0; j < 40; ++j) {
        int idx = j * 64 + lane;
        int r = idx / 40, cc = idx - r * 40;
        int gcol = ch0 + cc;
        float v = 0.f;
        if (gcol < 310) v = eeg[(bw + r) * 310 + gcol];
        sw[r * 41 + cc] = v;
    }
    SYNC();
    #pragma unroll
    for (int cc = 0; cc < 40; ++cc) {
        int gcol = ch0 + cc;
        if (gcol < 310)
            ws[WS_EEGT + gcol * NB + bw + lane] = sw[lane * 41 + cc];
    }
    #pragma unroll
    for (int el = 0; el < 8; ++el) {
        int e = chunk * 8 + el;
        if (e < 62) {
            const float* xr = sw + lane * 41 + el * 5;
            float p = (xr[0] + xr[1] + xr[2] + xr[3] + xr[4]) * 0.2f;
            ws[WS_POOL + e * NB + bw + lane] = p;
        }
    }
}

__global__ __launch_bounds__(256) void eog_tr(const float* __restrict__ eog,
                                              float* __restrict__ ws)
{
    __shared__ float smem[4 * 64 * 34];
    const int lane = threadIdx.x & 63;
    const int wid  = threadIdx.x >> 6;
    const int bw   = blockIdx.x * 256 + wid * 64;
    float* sw = smem + wid * (64 * 34);

    for (int j = 0; j < 33; ++j) {
        int idx = j * 64 + lane;
        int r = idx / 33, cc = idx - r * 33;
        sw[r * 34 + cc] = eog[(bw + r) * 33 + cc];
    }
    SYNC();
    #pragma unroll
    for (int cc = 0; cc < 33; ++cc)
        ws[WS_EOGT + cc * NB + bw + lane] = sw[lane * 34 + cc];
}

// ================= per-lane front-end: EEG + EOG -> featT[64][B] ===========
__global__ __launch_bounds__(256, 2) void mcaf_front(
    const float* __restrict__ eeg_cb,
    const float* __restrict__ eog_inw, const float* __restrict__ eog_inb,
    const float* __restrict__ eog_ow,  const float* __restrict__ eog_ob,
    const float* __restrict__ eog_cb,
    float* __restrict__ ws)
{
    const int b = blockIdx.x * 256 + threadIdx.x;

    float pooled[62];
    #pragma unroll
    for (int e = 0; e < 62; ++e) pooled[e] = ws[WS_POOL + e * NB + b];

    float h[32];
    #pragma unroll
    for (int o = 0; o < 32; ++o) h[o] = eeg_cb[o];

    for (int c = 0; c < 62; ++c) {
        const float* Mr = ws + WS_M + c * 62;
        float oc0 = ws[WS_OBB + c], oc1 = 0.f;
        #pragma unroll
        for (int e = 0; e < 62; e += 2) {
            oc0 = fmaf(Mr[e],     pooled[e],     oc0);
            oc1 = fmaf(Mr[e + 1], pooled[e + 1], oc1);
        }
        float oc = oc0 + oc1;
        const float* xb = ws + WS_EEGT + c * 5 * NB + b;
        float x0 = xb[0], x1 = xb[NB], x2 = xb[2 * NB], x3 = xb[3 * NB], x4 = xb[4 * NB];
        const float* cwr = ws + WS_CWT + c * 160;
        #pragma unroll
        for (int o = 0; o < 32; ++o) {
            float tt = x0 * cwr[o * 5 + 0];
            tt = fmaf(x1, cwr[o * 5 + 1], tt);
            tt = fmaf(x2, cwr[o * 5 + 2], tt);
            tt = fmaf(x3, cwr[o * 5 + 3], tt);
            tt = fmaf(x4, cwr[o * 5 + 4], tt);
            h[o] = fmaf(oc, tt, h[o]);
        }
    }
    #pragma unroll
    for (int o = 0; o < 32; ++o) h[o] = h[o] > 0.f ? h[o] : expm1f(h[o]);

    float feat[64];
    #pragma unroll
    for (int f = 0; f < 64; ++f) {
        float acc = ws[WS_B0 + f];
        #pragma unroll
        for (int o = 0; o < 32; ++o)
            acc = fmaf(ws[WS_A_EEG + f * 32 + o], h[o], acc);
        feat[f] = acc;
    }

    // ---- EOG branch ----
    {
        float Tg[32];
        #pragma unroll
        for (int o = 0; o < 32; ++o) Tg[o] = 0.f;
        float pool = 0.f;
        for (int l2 = 0; l2 < 33; ++l2) {
            float x = ws[WS_EOGT + l2 * NB + b];
            pool += x;
            const float* cr = ws + WS_CWOG + l2 * 32;
            #pragma unroll
            for (int o = 0; o < 32; ++o) Tg[o] = fmaf(x, cr[o], Tg[o]);
        }
        pool *= (1.f / 33.f);
        float vb2 = fmaf(pool, eog_inw[2], eog_inb[2]);
        float ob2 = fmaf(vb2, eog_ow[0], eog_ob[0]);
        #pragma unroll
        for (int o = 0; o < 32; ++o) {
            float hh = fmaf(ob2, Tg[o], eog_cb[o]);
            Tg[o] = hh > 0.f ? hh : expm1f(hh);
        }
        #pragma unroll
        for (int f = 0; f < 64; ++f) {
            float acc = feat[f];
            #pragma unroll
            for (int o = 0; o < 32; ++o)
                acc = fmaf(ws[WS_A_EOG + f * 32 + o], Tg[o], acc);
            feat[f] = acc;
        }
    }

    // store featT (overwrites dead eegT cols 0..63 for this b only)
    #pragma unroll
    for (int d = 0; d < 64; ++d)
        ws[WS_FEAT + d * NB + b] = feat[d];
}

// ================= transformer + head (wave-coop MFMA, barrier-free) =======
__global__ __launch_bounds__(256, 2) void mcaf_trans(
    const float* __restrict__ tl_ln1_s, const float* __restrict__ tl_ln1_b,
    const float* __restrict__ tl_ln2_s, const float* __restrict__ tl_ln2_b,
    const float* __restrict__ tl_b1,   const float* __restrict__ tl_b2,
    const float* __restrict__ fn_s,    const float* __restrict__ fn_b,
    const float* __restrict__ cls_w,   const float* __restrict__ cls_b,
    const float* __restrict__ ws,      float* __restrict__ out)
{
    __shared__ char smem[4 * WAVE_LDS];   // 53248 B -> 2 blocks/CU (grid-capped)
    const int tid  = threadIdx.x;
    const int lane = tid & 63;
    const int wid  = tid >> 6;
    const int b    = blockIdx.x * 256 + tid;
    char* Wv = smem + wid * WAVE_LDS;
    const int g4  = lane >> 4;
    const int r15 = lane & 15;

    float feat[64];
    #pragma unroll
    for (int d = 0; d < 64; ++d) feat[d] = ws[WS_FEAT + d * NB + b];

    const short* WAb = (const short*)(ws + WB_WA_F);
    const short* W1b = (const short*)(ws + WB_W1_F);
    const short* W2b = (const short*)(ws + WB_W2_F);

    for (int i2 = 0; i2 < 2; ++i2) {
        const float* ba  = ws + WS_BATT + i2 * 64;
        const float* s1  = tl_ln1_s + i2 * 64;
        const float* gb1 = tl_ln1_b + i2 * 64;
        const float* s2  = tl_ln2_s + i2 * 64;
        const float* gb2 = tl_ln2_b + i2 * 64;
        const float* bf1 = tl_b1 + i2 * 256;
        const float* bf2 = tl_b2 + i2 * 64;

        float hb[64];
        // LN1
        {
            float m = 0.f;
            #pragma unroll
            for (int d = 0; d < 64; ++d) m += feat[d];
            m *= 0.015625f;
            float vv = 0.f;
            #pragma unroll
            for (int d = 0; d < 64; ++d) { float u = feat[d] - m; vv = fmaf(u, u, vv); }
            vv *= 0.015625f;
            float inv = rsqrtf(vv + 1e-5f);
            #pragma unroll
            for (int d = 0; d < 64; ++d)
                hb[d] = fmaf((feat[d] - m) * inv, s1[d], gb1[d]);
        }
        // stage H rows (granules 0..7)
        #pragma unroll
        for (int jj = 0; jj < 8; ++jj) {
            bf16x8 v;
            #pragma unroll
            for (int e = 0; e < 8; ++e) v[e] = f2bf(hb[jj * 8 + e]);
            *(bf16x8*)(Wv + lane * ROWB + jj * 16) = v;
        }
        SYNC();
        bf16x8 Aat[4][2];
        #pragma unroll
        for (int rt = 0; rt < 4; ++rt)
            #pragma unroll
            for (int kt = 0; kt < 2; ++kt)
                Aat[rt][kt] = *(const bf16x8*)(Wv + (rt * 16 + r15) * ROWB + (kt * 4 + g4) * 16);
        SYNC();
        // attn GEMM: 64x64x64
        f32x4 acc[4][4];
        #pragma unroll
        for (int rt = 0; rt < 4; ++rt)
            #pragma unroll
            for (int ct = 0; ct < 4; ++ct) acc[rt][ct] = (f32x4){0.f, 0.f, 0.f, 0.f};
        #pragma unroll
        for (int kt = 0; kt < 2; ++kt) {
            bf16x8 bb[4];
            #pragma unroll
            for (int ct = 0; ct < 4; ++ct)
                bb[ct] = *(const bf16x8*)(WAb + i2 * 4096 + (ct * 16 + r15) * 64 + kt * 32 + g4 * 8);
            #pragma unroll
            for (int rt = 0; rt < 4; ++rt)
                #pragma unroll
                for (int ct = 0; ct < 4; ++ct)
                    acc[rt][ct] = __builtin_amdgcn_mfma_f32_16x16x32_bf16(Aat[rt][kt], bb[ct], acc[rt][ct], 0, 0, 0);
        }
        // C relayout halves + residual + folded bias
        #pragma unroll
        for (int hf = 0; hf < 2; ++hf) {
            SYNC();
            #pragma unroll
            for (int ct2 = 0; ct2 < 2; ++ct2) {
                int ct = hf * 2 + ct2;
                #pragma unroll
                for (int rt = 0; rt < 4; ++rt)
                    #pragma unroll
                    for (int rg = 0; rg < 4; ++rg) {
                        int row = rt * 16 + g4 * 4 + rg;
                        int lc  = ct2 * 16 + r15;
                        *(float*)(Wv + row * ROWB + lc * 4) = acc[rt][ct][rg];
                    }
            }
            SYNC();
            #pragma unroll
            for (int j8 = 0; j8 < 8; ++j8) {
                f32x4 v = *(const f32x4*)(Wv + lane * ROWB + j8 * 16);
                #pragma unroll
                for (int e = 0; e < 4; ++e) {
                    int d = hf * 32 + j8 * 4 + e;
                    feat[d] += v[e] + ba[d];
                }
            }
        }
        // LN2
        {
            float m = 0.f;
            #pragma unroll
            for (int d = 0; d < 64; ++d) m += feat[d];
            m *= 0.015625f;
            float vv = 0.f;
            #pragma unroll
            for (int d = 0; d < 64; ++d) { float u = feat[d] - m; vv = fmaf(u, u, vv); }
            vv *= 0.015625f;
            float inv = rsqrtf(vv + 1e-5f);
            #pragma unroll
            for (int d = 0; d < 64; ++d)
                hb[d] = fmaf((feat[d] - m) * inv, s2[d], gb2[d]);
        }
        SYNC();
        #pragma unroll
        for (int jj = 0; jj < 8; ++jj) {
            bf16x8 v;
            #pragma unroll
            for (int e = 0; e < 8; ++e) v[e] = f2bf(hb[jj * 8 + e]);
            *(bf16x8*)(Wv + lane * ROWB + jj * 16) = v;
        }
        SYNC();
        // FFN: 8 chunks of 32 hidden; F accumulates FFN2
        f32x4 F[4][4];
        #pragma unroll
        for (int rt = 0; rt < 4; ++rt)
            #pragma unroll
            for (int ct = 0; ct < 4; ++ct) F[rt][ct] = (f32x4){0.f, 0.f, 0.f, 0.f};

        for (int ch = 0; ch < 8; ++ch) {
            f32x4 G[4][2];
            #pragma unroll
            for (int rt = 0; rt < 4; ++rt) {
                G[rt][0] = (f32x4){0.f, 0.f, 0.f, 0.f};
                G[rt][1] = (f32x4){0.f, 0.f, 0.f, 0.f};
            }
            #pragma unroll
            for (int kt = 0; kt < 2; ++kt) {
                bf16x8 a1[4];
                #pragma unroll
                for (int rt = 0; rt < 4; ++rt)
                    a1[rt] = *(const bf16x8*)(Wv + (rt * 16 + r15) * ROWB + (kt * 4 + g4) * 16);
                bf16x8 b1[2];
                #pragma unroll
                for (int cc = 0; cc < 2; ++cc)
                    b1[cc] = *(const bf16x8*)(W1b + i2 * 16384 + (ch * 32 + cc * 16 + r15) * 64 + kt * 32 + g4 * 8);
                #pragma unroll
                for (int rt = 0; rt < 4; ++rt)
                    #pragma unroll
                    for (int cc = 0; cc < 2; ++cc)
                        G[rt][cc] = __builtin_amdgcn_mfma_f32_16x16x32_bf16(a1[rt], b1[cc], G[rt][cc], 0, 0, 0);
            }
            SYNC();
            // bias + gelu -> G' bf16 (granules 8..11)
            #pragma unroll
            for (int rt = 0; rt < 4; ++rt)
                #pragma unroll
                for (int cc = 0; cc < 2; ++cc) {
                    float bj = bf1[ch * 32 + cc * 16 + r15];
                    #pragma unroll
                    for (int rg = 0; rg < 4; ++rg) {
                        float v = G[rt][cc][rg] + bj;
                        v = 0.5f * v * (1.f + erff(v * 0.70710678118654752f));
                        int row = rt * 16 + g4 * 4 + rg;
                        int col = cc * 16 + r15;
                        *(short*)(Wv + row * ROWB + 128 + ((col >> 3) << 4) + ((col & 7) << 1)) = f2bf(v);
                    }
                }
            SYNC();
            bf16x8 a2[4], b2[4];
            #pragma unroll
            for (int rt = 0; rt < 4; ++rt)
                a2[rt] = *(const bf16x8*)(Wv + (rt * 16 + r15) * ROWB + 128 + g4 * 16);
            #pragma unroll
            for (int ct = 0; ct < 4; ++ct)
                b2[ct] = *(const bf16x8*)(W2b + i2 * 16384 + (ct * 16 + r15) * 256 + ch * 32 + g4 * 8);
            #pragma unroll
            for (int rt = 0; rt < 4; ++rt)
                #pragma unroll
                for (int ct = 0; ct < 4; ++ct)
                    F[rt][ct] = __builtin_amdgcn_mfma_f32_16x16x32_bf16(a2[rt], b2[ct], F[rt][ct], 0, 0, 0);
            SYNC();   // order a2 reads before next chunk's G' writes
        }
        // F relayout halves + residual + b2 bias
        #pragma unroll
        for (int hf = 0; hf < 2; ++hf) {
            SYNC();
            #pragma unroll
            for (int ct2 = 0; ct2 < 2; ++ct2) {
                int ct = hf * 2 + ct2;
                #pragma unroll
                for (int rt = 0; rt < 4; ++rt)
                    #pragma unroll
                    for (int rg = 0; rg < 4; ++rg) {
                        int row = rt * 16 + g4 * 4 + rg;
                        int lc  = ct2 * 16 + r15;
                        *(float*)(Wv + row * ROWB + lc * 4) = F[rt][ct][rg];
                    }
            }
            SYNC();
            #pragma unroll
            for (int j8 = 0; j8 < 8; ++j8) {
                f32x4 v = *(const f32x4*)(Wv + lane * ROWB + j8 * 16);
                #pragma unroll
                for (int e = 0; e < 4; ++e) {
                    int d = hf * 32 + j8 * 4 + e;
                    feat[d] += v[e] + bf2[d];
                }
            }
        }
        SYNC();
    }

    // ---- final LN + classifier ----
    {
        float m = 0.f;
        #pragma unroll
        for (int d = 0; d < 64; ++d) m += feat[d];
        m *= 0.015625f;
        float vv = 0.f;
        #pragma unroll
        for (int d = 0; d < 64; ++d) { float u = feat[d] - m; vv = fmaf(u, u, vv); }
        vv *= 0.015625f;
        float inv = rsqrtf(vv + 1e-5f);
        float o0 = cls_b[0], o1 = cls_b[1], o2 = cls_b[2];
        #pragma unroll
        for (int d = 0; d < 64; ++d) {
            float n = fmaf((feat[d] - m) * inv, fn_s[d], fn_b[d]);
            o0 = fmaf(n, cls_w[d], o0);
            o1 = fmaf(n, cls_w[64 + d], o1);
            o2 = fmaf(n, cls_w[128 + d], o2);
        }
        float* op = out + b * 3;
        op[0] = o0; op[1] = o1; op[2] = o2;
    }
}

// ================= fallback main kernel (fp32, LDS staging) =================
__global__ __launch_bounds__(256, 2) void mcaf_main_fb(
    const float* __restrict__ eeg,     const float* __restrict__ eog,
    const float* __restrict__ eeg_inb,
    const float* __restrict__ eeg_ow,  const float* __restrict__ eeg_ob,
    const float* __restrict__ eog_inw, const float* __restrict__ eog_inb,
    const float* __restrict__ eog_ow,  const float* __restrict__ eog_ob,
    const float* __restrict__ eeg_cb,  const float* __restrict__ eog_cb,
    const float* __restrict__ tl_ln1_s, const float* __restrict__ tl_ln1_b,
    const float* __restrict__ tl_ln2_s, const float* __restrict__ tl_ln2_b,
    const float* __restrict__ tl_w1,   const float* __restrict__ tl_b1,
    const float* __restrict__ tl_b2,
    const float* __restrict__ fn_s,    const float* __restrict__ fn_b,
    const float* __restrict__ cls_w,   const float* __restrict__ cls_b,
    const float* __restrict__ ws,      float* __restrict__ out)
{
    __shared__ float smem[4 * 64 * 41];
    const int t    = threadIdx.x;
    const int lane = t & 63;
    const int wid  = t >> 6;
    const int bw   = blockIdx.x * 256 + wid * 64;
    const int b    = bw + lane;
    float* sw = smem + wid * (64 * 41);

    float vbar[62];
    #pragma unroll
    for (int d = 0; d < 62; ++d) vbar[d] = eeg_inb[124 + d];

    for (int chunk = 0; chunk < 8; ++chunk) {
        const int ch0 = chunk * 8;
        for (int j = 0; j < 40; ++j) {
            int idx = j * 64 + lane;
            int r = idx / 40, cc = idx - r * 40;
            int gcol = ch0 * 5 + cc;
            float v = 0.f;
            if (gcol < 310) v = eeg[(bw + r) * 310 + gcol];
            sw[r * 41 + cc] = v;
        }
        __syncthreads();
        const int nch = (62 - ch0 < 8) ? (62 - ch0) : 8;
        for (int el = 0; el < nch; ++el) {
            const int e = ch0 + el;
            const float* xr = sw + lane * 41 + el * 5;
            float p = (xr[0] + xr[1] + xr[2] + xr[3] + xr[4]) * 0.2f;
            const float* wr = ws + WS_WVT + e * 62;
            #pragma unroll
            for (int d = 0; d < 62; ++d) vbar[d] = fmaf(p, wr[d], vbar[d]);
        }
        __syncthreads();
    }

    float h[32];
    #pragma unroll
    for (int o = 0; o < 32; ++o) h[o] = eeg_cb[o];

    for (int chunk = 0; chunk < 8; ++chunk) {
        const int ch0 = chunk * 8;
        for (int j = 0; j < 40; ++j) {
            int idx = j * 64 + lane;
            int r = idx / 40, cc = idx - r * 40;
            int gcol = ch0 * 5 + cc;
            float v = 0.f;
            if (gcol < 310) v = eeg[(bw + r) * 310 + gcol];
            sw[r * 41 + cc] = v;
        }
        __syncthreads();
        const int nch = (62 - ch0 < 8) ? (62 - ch0) : 8;
        for (int el = 0; el < nch; ++el) {
            const int c = ch0 + el;
            const float* owr = eeg_ow + c * 62;
            float oc = eeg_ob[c];
            #pragma unroll
            for (int d = 0; d < 62; ++d) oc = fmaf(owr[d], vbar[d], oc);
            const float* xr = sw + lane * 41 + el * 5;
            float x0 = xr[0], x1 = xr[1], x2 = xr[2], x3 = xr[3], x4 = xr[4];
            const float* cwr = ws + WS_CWT + c * 160;
            #pragma unroll
            for (int o = 0; o < 32; ++o) {
                float tt = x0 * cwr[o * 5 + 0];
                tt = fmaf(x1, cwr[o * 5 + 1], tt);
                tt = fmaf(x2, cwr[o * 5 + 2], tt);
                tt = fmaf(x3, cwr[o * 5 + 3], tt);
                tt = fmaf(x4, cwr[o * 5 + 4], tt);
                h[o] = fmaf(oc, tt, h[o]);
            }
        }
        __syncthreads();
    }

    #pragma unroll
    for (int o = 0; o < 32; ++o) h[o] = h[o] > 0.f ? h[o] : expm1f(h[o]);

    float feat[64];
    #pragma unroll
    for (int f = 0; f < 64; ++f) {
        float acc = ws[WS_B0 + f];
        #pragma unroll
        for (int o = 0; o < 32; ++o)
            acc = fmaf(ws[WS_A_EEG + f * 32 + o], h[o], acc);
        feat[f] = acc;
    }

    for (int j = 0; j < 33; ++j) {
        int idx = j * 64 + lane;
        int r = idx / 33, cc = idx - r * 33;
        sw[r * 34 + cc] = eog[(bw + r) * 33 + cc];
    }
    __syncthreads();
    {
        float Tg[32];
        #pragma unroll
        for (int o = 0; o < 32; ++o) Tg[o] = 0.f;
        float pool = 0.f;
        for (int l2 = 0; l2 < 33; ++l2) {
            float x = sw[lane * 34 + l2];
            pool += x;
            const float* cr = ws + WS_CWOG + l2 * 32;
            #pragma unroll
            for (int o = 0; o < 32; ++o) Tg[o] = fmaf(x, cr[o], Tg[o]);
        }
        pool *= (1.f / 33.f);
        float vb2 = fmaf(pool, eog_inw[2], eog_inb[2]);
        float ob2 = fmaf(vb2, eog_ow[0], eog_ob[0]);
        #pragma unroll
        for (int o = 0; o < 32; ++o) {
            float hh = fmaf(ob2, Tg[o], eog_cb[o]);
            Tg[o] = hh > 0.f ? hh : expm1f(hh);
        }
        #pragma unroll
        for (int f = 0; f < 64; ++f) {
            float acc = feat[f];
            #pragma unroll
            for (int o = 0; o < 32; ++o)
                acc = fmaf(ws[WS_A_EOG + f * 32 + o], Tg[o], acc);
            feat[f] = acc;
        }
    }

    for (int i2 = 0; i2 < 2; ++i2) {
        const float* Wa  = ws + WS_WATT + i2 * 4096;
        const float* ba  = ws + WS_BATT + i2 * 64;
        const float* s1  = tl_ln1_s + i2 * 64;
        const float* g1  = tl_ln1_b + i2 * 64;
        const float* s2  = tl_ln2_s + i2 * 64;
        const float* g2  = tl_ln2_b + i2 * 64;
        const float* w1p = tl_w1 + i2 * 16384;
        const float* bf1 = tl_b1 + i2 * 256;
        const float* w2t = ws + WS_W2T + i2 * 16384;
        const float* bf2 = tl_b2 + i2 * 64;

        float hb[64];
        {
            float m = 0.f;
            #pragma unroll
            for (int d = 0; d < 64; ++d) m += feat[d];
            m *= 0.015625f;
            float vv = 0.f;
            #pragma unroll
            for (int d = 0; d < 64; ++d) { float u = feat[d] - m; vv = fmaf(u, u, vv); }
            vv *= 0.015625f;
            float inv = rsqrtf(vv + 1e-5f);
            #pragma unroll
            for (int d = 0; d < 64; ++d)
                hb[d] = fmaf((feat[d] - m) * inv, s1[d], g1[d]);
        }
        #pragma unroll
        for (int c = 0; c < 64; ++c) {
            float a = ba[c];
            #pragma unroll
            for (int d = 0; d < 64; ++d) a = fmaf(Wa[c * 64 + d], hb[d], a);
            feat[c] += a;
        }
        {
            float m = 0.f;
            #pragma unroll
            for (int d = 0; d < 64; ++d) m += feat[d];
            m *= 0.015625f;
            float vv = 0.f;
            #pragma unroll
            for (int d = 0; d < 64; ++d) { float u = feat[d] - m; vv = fmaf(u, u, vv); }
            vv *= 0.015625f;
            float inv = rsqrtf(vv + 1e-5f);
            #pragma unroll
            for (int d = 0; d < 64; ++d)
                hb[d] = fmaf((feat[d] - m) * inv, s2[d], g2[d]);
        }
        #pragma unroll
        for (int c = 0; c < 64; ++c) feat[c] += bf2[c];
        for (int j = 0; j < 256; ++j) {
            const float* wr = w1p + j * 64;
            float g = bf1[j];
            #pragma unroll
            for (int d = 0; d < 64; ++d) g = fmaf(wr[d], hb[d], g);
            g = 0.5f * g * (1.f + erff(g * 0.70710678118654752f));
            const float* w2r = w2t + j * 64;
            #pragma unroll
            for (int c = 0; c < 64; ++c) feat[c] = fmaf(g, w2r[c], feat[c]);
        }
    }

    {
        float m = 0.f;
        #pragma unroll
        for (int d = 0; d < 64; ++d) m += feat[d];
        m *= 0.015625f;
        float vv = 0.f;
        #pragma unroll
        for (int d = 0; d < 64; ++d) { float u = feat[d] - m; vv = fmaf(u, u, vv); }
        vv *= 0.015625f;
        float inv = rsqrtf(vv + 1e-5f);
        float o0 = cls_b[0], o1 = cls_b[1], o2 = cls_b[2];
        #pragma unroll
        for (int d = 0; d < 64; ++d) {
            float n = fmaf((feat[d] - m) * inv, fn_s[d], fn_b[d]);
            o0 = fmaf(n, cls_w[d], o0);
            o1 = fmaf(n, cls_w[64 + d], o1);
            o2 = fmaf(n, cls_w[128 + d], o2);
        }
        float* op = out + b * 3;
        op[0] = o0; op[1] = o1; op[2] = o2;
    }
}

extern "C" void kernel_launch(void* const* d_in, const int* in_sizes, int n_in,
                              void* d_out, int out_size, void* d_ws, size_t ws_size,
                              hipStream_t stream) {
    const float* eeg      = (const float*)d_in[0];
    const float* eog      = (const float*)d_in[1];
    const float* eeg_inw  = (const float*)d_in[2];
    const float* eeg_inb  = (const float*)d_in[3];
    const float* eeg_ow   = (const float*)d_in[4];
    const float* eeg_ob   = (const float*)d_in[5];
    const float* eog_inw  = (const float*)d_in[6];
    const float* eog_inb  = (const float*)d_in[7];
    const float* eog_ow   = (const float*)d_in[8];
    const float* eog_ob   = (const float*)d_in[9];
    const float* eeg_cw   = (const float*)d_in[10];
    const float* eeg_cb   = (const float*)d_in[11];
    const float* eeg_fw   = (const float*)d_in[12];
    const float* eeg_fb   = (const float*)d_in[13];
    const float* eog_cw   = (const float*)d_in[14];
    const float* eog_cb   = (const float*)d_in[15];
    const float* eog_fw   = (const float*)d_in[16];
    const float* eog_fb   = (const float*)d_in[17];
    const float* fus_w    = (const float*)d_in[18];
    const float* fus_b    = (const float*)d_in[19];
    const float* tl_ln1_s = (const float*)d_in[20];
    const float* tl_ln1_b = (const float*)d_in[21];
    const float* tl_inw   = (const float*)d_in[22];
    const float* tl_inb   = (const float*)d_in[23];
    const float* tl_ow    = (const float*)d_in[24];
    const float* tl_ob    = (const float*)d_in[25];
    const float* tl_ln2_s = (const float*)d_in[26];
    const float* tl_ln2_b = (const float*)d_in[27];
    const float* tl_w1    = (const float*)d_in[28];
    const float* tl_b1    = (const float*)d_in[29];
    const float* tl_w2    = (const float*)d_in[30];
    const float* tl_b2    = (const float*)d_in[31];
    const float* fn_s     = (const float*)d_in[32];
    const float* fn_b     = (const float*)d_in[33];
    const float* cls_w    = (const float*)d_in[34];
    const float* cls_b    = (const float*)d_in[35];
    float* ws  = (float*)d_ws;
    float* out = (float*)d_out;

    hipLaunchKernelGGL(mcaf_pre, dim3(8), dim3(256), 0, stream,
                       eeg_inw, eeg_inb, eeg_ow, eeg_ob, eeg_cw,
                       eeg_fw, eeg_fb, eog_cw, eog_fw, eog_fb,
                       fus_w, fus_b, tl_inw, tl_inb, tl_ow, tl_ob, tl_w1, tl_w2, ws);

    const size_t need = (size_t)WS_TOTALF * 4u;
    if (ws_size >= need) {
        hipLaunchKernelGGL(eeg_tr, dim3((NB / 256) * 8), dim3(256), 0, stream, eeg, ws);
        hipLaunchKernelGGL(eog_tr, dim3(NB / 256), dim3(256), 0, stream, eog, ws);
        hipLaunchKernelGGL(mcaf_front, dim3(NB / 256), dim3(256), 0, stream,
                           eeg_cb, eog_inw, eog_inb, eog_ow, eog_ob, eog_cb, ws);
        hipLaunchKernelGGL(mcaf_trans, dim3(NB / 256), dim3(256), 0, stream,
                           tl_ln1_s, tl_ln1_b, tl_ln2_s, tl_ln2_b,
                           tl_b1, tl_b2, fn_s, fn_b, cls_w, cls_b, ws, out);
    } else {
        hipLaunchKernelGGL(mcaf_main_fb, dim3(NB / 256), dim3(256), 0, stream,
                           eeg, eog, eeg_inb, eeg_ow, eeg_ob,
                           eog_inw, eog_inb, eog_ow, eog_ob,
                           eeg_cb, eog_cb,
                           tl_ln1_s, tl_ln1_b, tl_ln2_s, tl_ln2_b,
                           tl_w1, tl_b1, tl_b2,
                           fn_s, fn_b, cls_w, cls_b, ws, out);
    }
}